// Round 8
// baseline (140.144 us; speedup 1.0000x reference)
//
#include <hip/hip_runtime.h>
#include <hip/hip_bf16.h>
#include <math.h>

// Problem constants (from reference)
constexpr int B = 8;
constexpr int S = 2048;
constexpr int D = 512;
constexpr int P = 64;
constexpr float SCALE = 0.125f;  // 1/sqrt(P)

typedef short bf16x8 __attribute__((ext_vector_type(8)));
typedef float f32x4 __attribute__((ext_vector_type(4)));
typedef unsigned int u32;

__device__ __forceinline__ unsigned short f2bf(float x) {
  __hip_bfloat16 h = __float2bfloat16(x);
  return __builtin_bit_cast(unsigned short, h);
}
__device__ __forceinline__ float bf2f(unsigned short u) {
  unsigned int v = (unsigned int)u << 16;
  return __builtin_bit_cast(float, v);
}

// Async global->LDS, 16B/lane; LDS dest = wave-uniform base + lane*16.
__device__ __forceinline__ void ld_g2lds16(const unsigned short* g,
                                           unsigned short* l) {
  __builtin_amdgcn_global_load_lds(
      (const __attribute__((address_space(1))) u32*)g,
      (__attribute__((address_space(3))) u32*)l, 16, 0, 0);
}

// ===========================================================================
// Fragment-packed layouts (as r6/r7): every MFMA fragment = contiguous
// 64-lane x 16 B = 1 KB lane-ordered chunk.
//  Bfrag  [12 nt][16 k16][64 lane][8]
//  Wofrag [32 ct][2 h][64 lane][8]
//  qfrag/kfrag [b][128 tile][2 h][64][8]     (tile = 16 rows, h = K-half)
//  vfrag  [b][64 tb][4 pc][64][8]            (tb = 32 t's, t is the K dim)
// NEW (r8): consumers stage these through LDS with BLOCK-level reuse.
// Evidence: r6/r7 both kernels plateau at ~5.5 TB/s of L3 traffic (cross-XCD
// dirty lines can't be L2-served).  Fix = fewer bytes: 128-row attn blocks
// (k/v fetched once per block: 256->64 MB), 64-row qkv blocks (192->48 MB).
// ===========================================================================

// ---------------------------------------------------------------------------
// Kernel 0: weight prep -> fragment-packed bf16 (unchanged).
// ---------------------------------------------------------------------------
__global__ __launch_bounds__(256) void prep_w(
    const float* __restrict__ Wq, const float* __restrict__ Wk,
    const float* __restrict__ Wv, const float* __restrict__ Wo,
    unsigned short* __restrict__ Bfrag, unsigned short* __restrict__ Wofrag) {
  const int i = blockIdx.x * 256 + threadIdx.x;
  if (i < 192 * 512) {
    const int d = i / 192;        // K index 0..511
    const int n = i - d * 192;    // output col 0..191
    const float* W = (n < 64) ? Wq : (n < 128) ? Wk : Wv;
    const float val = W[d * 64 + (n & 63)];
    const int nt = n >> 4, l15 = n & 15;
    const int k16 = d >> 5, l4 = (d >> 3) & 3, j = d & 7;
    Bfrag[(((nt * 16 + k16) * 4 + l4) * 16 + l15) * 8 + j] = f2bf(val);
  }
  if (i < 64 * 512) {
    const int k = i >> 9;   // 0..63   (P dim)
    const int n = i & 511;  // 0..511  (D dim)
    const float val = Wo[k * 512 + n];
    const int ct = n >> 4, l15 = n & 15;
    const int h = k >> 5, l4 = (k >> 3) & 3, j = k & 7;
    Wofrag[(((ct * 2 + h) * 4 + l4) * 16 + l15) * 8 + j] = f2bf(val);
  }
}

// ---------------------------------------------------------------------------
// Kernel 1: QKV projection (v4).  Grid 256 x 512 thr (8 waves).
// Block = 64 rows x 192 cols; wave = (rg=w&3: 16-row subtile) x (ch=w>>2:
// 96 cols = 6 n-tiles).  A (64x512 bf16, 64 KB LDS) converted once.
// Bfrag staged per-64-K-chunk via global_load_lds, double-buffered (2x24 KB):
// block fetches Bfrag ONCE (192 KB) -> chip-wide 48 MB (was 192).
// Chunk order staggered by blockIdx&7 (accumulation commutes).
// ---------------------------------------------------------------------------
__global__ __launch_bounds__(512, 2) void qkv_mfma(
    const float* __restrict__ query, const unsigned short* __restrict__ Bfrag,
    const float* __restrict__ bq, const float* __restrict__ bk,
    const float* __restrict__ bv, unsigned short* __restrict__ qfrag,
    unsigned short* __restrict__ kfrag, unsigned short* __restrict__ vfrag) {
  __shared__ __align__(16) unsigned short Aq[64 * 512];     // 64 KB swizzled
  __shared__ __align__(16) unsigned short Bb[2][24 * 512];  // 48 KB

  const int tid = threadIdx.x;
  const int w = tid >> 6;   // 0..7
  const int l = tid & 63;
  const int l15 = l & 15;
  const int l4 = l >> 4;
  const int s0 = blockIdx.x * 64;
  const int rg = w & 3;
  const int ch = w >> 2;
  const int phase = blockIdx.x & 7;

  // ---- Prologue: 64 query rows fp32 -> bf16 swizzled LDS tile.
  const float* qsrc = query + (size_t)s0 * D;
#pragma unroll
  for (int step = 0; step < 8; ++step) {
    const int row = step * 8 + w;  // wave-uniform
    const float* pf = qsrc + row * D + l * 8;
    const float4 x = *(const float4*)pf;
    const float4 y = *(const float4*)(pf + 4);
    bf16x8 u;
    u[0] = (short)f2bf(x.x); u[1] = (short)f2bf(x.y);
    u[2] = (short)f2bf(x.z); u[3] = (short)f2bf(x.w);
    u[4] = (short)f2bf(y.x); u[5] = (short)f2bf(y.y);
    u[6] = (short)f2bf(y.z); u[7] = (short)f2bf(y.w);
    *(bf16x8*)&Aq[row * 512 + ((l ^ (row & 7)) << 3)] = u;
  }

  // ---- Stage one 64-K chunk (24 x 1KB) into buf: wave w stages cid=w*3+i.
  // Chunk kc covers k16 = {2kc, 2kc+1} for all 12 n-tiles.
  // LDS layout: [nt][kb][lane][8]  (cid = nt*2+kb).
#define STAGE_B(kc, buf)                                                      \
  {                                                                           \
    _Pragma("unroll") for (int i = 0; i < 3; ++i) {                           \
      const int cid = w * 3 + i;                                              \
      const int nt = cid >> 1, kb = cid & 1;                                  \
      const unsigned short* gp =                                              \
          Bfrag + (size_t)(nt * 16 + (kc)*2 + kb) * 512 + (size_t)l * 8;      \
      ld_g2lds16(gp, &Bb[buf][cid * 512]);                                    \
    }                                                                         \
  }

  STAGE_B(phase, 0);
  __syncthreads();  // A-tile writes + chunk 0 staged

  f32x4 acc[6];
#pragma unroll
  for (int j = 0; j < 6; ++j) acc[j] = (f32x4){0.f, 0.f, 0.f, 0.f};

  for (int it = 0; it < 8; ++it) {
    const int kc = (it + phase) & 7;
    if (it < 7) STAGE_B((it + 1 + phase) & 7, (it + 1) & 1);
    const unsigned short* Bcur = &Bb[it & 1][0];
#pragma unroll
    for (int kb = 0; kb < 2; ++kb) {
      const int row = rg * 16 + l15;
      const int slot = ((kc * 2 + kb) * 4 + l4) ^ (row & 7);
      const bf16x8 af = *(const bf16x8*)&Aq[row * 512 + (slot << 3)];
#pragma unroll
      for (int j = 0; j < 6; ++j) {
        const bf16x8 bfr =
            *(const bf16x8*)&Bcur[((ch * 6 + j) * 2 + kb) * 512 + l * 8];
        acc[j] =
            __builtin_amdgcn_mfma_f32_16x16x32_bf16(af, bfr, acc[j], 0, 0, 0);
      }
    }
    __syncthreads();  // stage(it+1) done; reads of Bcur done
  }

  // ---- Epilogue: bias + scatter into fragment-packed q/k/v.
  const int b = s0 >> 11;
  const size_t bbase = (size_t)b * (S * P);
#pragma unroll
  for (int j = 0; j < 6; ++j) {
    const int col = ch * 96 + j * 16 + l15;
    const int mat = col >> 6;  // uniform per (ch,j)
    const int p = col & 63;
    const float bb = ((mat == 0) ? bq : (mat == 1) ? bk : bv)[p];
#pragma unroll
    for (int r = 0; r < 4; ++r) {
      const int s = s0 + rg * 16 + l4 * 4 + r;
      const int t = s & 2047;
      const float vl = acc[j][r] + bb;
      if (mat == 2) {  // v: [tb][pc][lane][8]
        const int tb = t >> 5, chv = (t >> 3) & 3, jv = t & 7;
        const int pcv = p >> 4, rowv = p & 15;
        vfrag[bbase + (((size_t)(tb * 4 + pcv) * 4 + chv) * 16 + rowv) * 8 +
              jv] = f2bf(vl);
      } else {  // q/k: [tile][h][lane][8]
        const int tile = t >> 4, rowin = t & 15;
        const int h = p >> 5, chp = (p >> 3) & 3, jj = p & 7;
        unsigned short* dst = (mat == 0) ? qfrag : kfrag;
        dst[bbase + (((size_t)(tile * 2 + h) * 4 + chp) * 16 + rowin) * 8 +
            jj] = f2bf(mat == 0 ? vl * SCALE : vl);
      }
    }
  }
#undef STAGE_B
}

// ---------------------------------------------------------------------------
// Kernel 2: flash attention + fused output projection (v8).
// Grid 128 x 1024 thr (16 waves = 4/SIMD; ~117 KB LDS -> 1 block/CU).
// Block = 128 q-rows of one batch (blk&7 = batch).  Waves = (qg=w&3: 32-row
// group) x (th=w>>2: 32-t slice of the 128-t window).  16 windows; k+v
// (32 KB/window) staged ONCE per block via global_load_lds double buffer
// (2 issues/wave/window, 1 barrier/window) -> k/v cache traffic 64 MB chip
// (was 256).  Per window per wave: QK 8 MFMA -> exp 16 -> e-tile (per-wave
// LDS) -> PV 8 MFMA.  Window order staggered by q-tile (sums commute).
// Epilogue: 4-way th combine (pacc aliases k/v+e LDS), normalize -> bf16,
// out = wnorm @ Wo + bo from Wofrag.
// ---------------------------------------------------------------------------
__global__ __launch_bounds__(1024, 4) void attn_fused(
    const unsigned short* __restrict__ qfrag,
    const unsigned short* __restrict__ kfrag,
    const unsigned short* __restrict__ vfrag,
    const unsigned short* __restrict__ Wofrag, const float* __restrict__ bo,
    float* __restrict__ out) {
  // [0,32K): k dbuf | [32K,64K): v dbuf | [64K,96K): e (16 waves x 2 KB)
  // epilogue alias: pacc [4qg][3][32][64] f32 = 96 KB at 0;
  //                 wnorm [128][72] bf16 = 18 KB at 96K.
  __shared__ __align__(16) unsigned char smem[116736];
  __shared__ float l_s[16][32];

  const int tid = threadIdx.x;
  const int w = tid >> 6;
  const int lane = tid & 63;
  const int l15 = lane & 15;
  const int l4 = lane >> 4;
  const int qg = w & 3;   // 32-row group
  const int th = w >> 2;  // 32-t slice of each window

  const int blk = blockIdx.x;
  const int b = blk & 7;
  const int s0 = (blk >> 3) * 128;
  const int phase = (blk >> 3) & 15;  // window stagger

  const size_t bbase = (size_t)b * (S * P);
  const unsigned short* qf = qfrag + bbase;
  const unsigned short* kf = kfrag + bbase;
  const unsigned short* vf = vfrag + bbase;

  unsigned short* kb0 = (unsigned short*)smem;              // [2][8192]
  unsigned short* vb0 = (unsigned short*)(smem + 32768);    // [2][8192]
  unsigned short* e_w = (unsigned short*)(smem + 65536) + w * 1024;

  // q A-fragments: rows qg*32 + st*16 + l15.
  bf16x8 aq[2][2];
#pragma unroll
  for (int st = 0; st < 2; ++st)
#pragma unroll
    for (int h = 0; h < 2; ++h)
      aq[st][h] =
          *(const bf16x8*)(qf +
                           ((size_t)(((s0 >> 4) + qg * 2 + st) * 2 + h) * 64 +
                            lane) *
                               8);

  f32x4 acc[2][4];
#pragma unroll
  for (int st = 0; st < 2; ++st)
#pragma unroll
    for (int pc = 0; pc < 4; ++pc) acc[st][pc] = (f32x4){0.f, 0.f, 0.f, 0.f};
  float lpart[2][4] = {{0.f, 0.f, 0.f, 0.f}, {0.f, 0.f, 0.f, 0.f}};

  // Stage window wi into buf: k 16 KB (wave w: tile_local=w>>1, h=w&1),
  //                           v 16 KB (wave w: tbl=w>>2, pc=w&3).
#define STAGE_KV(wi, buf)                                                     \
  {                                                                           \
    const int t0s = (wi)*128;                                                 \
    const unsigned short* gpk =                                               \
        kf + ((size_t)((t0s >> 4) + (w >> 1)) * 2 + (w & 1)) * 512 +          \
        (size_t)lane * 8;                                                     \
    ld_g2lds16(gpk, kb0 + (buf)*8192 + w * 512);                              \
    const unsigned short* gpv =                                               \
        vf + ((size_t)((t0s >> 5) + (w >> 2)) * 4 + (w & 3)) * 512 +          \
        (size_t)lane * 8;                                                     \
    ld_g2lds16(gpv, vb0 + (buf)*8192 + w * 512);                              \
  }

  STAGE_KV(phase, 0);
  __syncthreads();

  for (int it = 0; it < 16; ++it) {
    if (it < 15) STAGE_KV((it + 1 + phase) & 15, (it + 1) & 1);
    const unsigned short* kt = kb0 + (it & 1) * 8192 + th * 2048;
    const unsigned short* vt = vb0 + (it & 1) * 8192 + th * 2048;

    // k fragments for this wave's 32-t slice (2 n-tiles x 2 K-halves).
    bf16x8 bk[2][2];
#pragma unroll
    for (int nt = 0; nt < 2; ++nt)
#pragma unroll
      for (int h = 0; h < 2; ++h)
        bk[nt][h] = *(const bf16x8*)&kt[nt * 1024 + h * 512 + lane * 8];
    // v fragments (K = 32 t's of this slice).
    bf16x8 bv[4];
#pragma unroll
    for (int pc = 0; pc < 4; ++pc)
      bv[pc] = *(const bf16x8*)&vt[pc * 512 + lane * 8];

#pragma unroll
    for (int st = 0; st < 2; ++st) {
      // QK^T: 16 rows x 32 t.
      f32x4 sc[2];
#pragma unroll
      for (int nt = 0; nt < 2; ++nt) {
        f32x4 c = (f32x4){0.f, 0.f, 0.f, 0.f};
        c = __builtin_amdgcn_mfma_f32_16x16x32_bf16(aq[st][0], bk[nt][0], c, 0,
                                                    0, 0);
        sc[nt] = __builtin_amdgcn_mfma_f32_16x16x32_bf16(aq[st][1], bk[nt][1],
                                                         c, 0, 0, 0);
      }
      // exp -> bf16 e-tile [16][32], chunk-XOR swizzled.
#pragma unroll
      for (int nt = 0; nt < 2; ++nt) {
        const int chl = nt * 2 + (l15 >> 3);  // logical chunk 0..3
#pragma unroll
        for (int r = 0; r < 4; ++r) {
          const int rr = l4 * 4 + r;
          const unsigned short eu = f2bf(__expf(sc[nt][r]));
          lpart[st][r] += bf2f(eu);
          e_w[st * 512 + rr * 32 + ((chl ^ (rr & 3)) << 3) + (l15 & 7)] = eu;
        }
      }
      // PV: A = e-tile (row l15, phys chunk l4^(l15&3)), B = v.
      const bf16x8 ae =
          *(const bf16x8*)&e_w[st * 512 + l15 * 32 + ((l4 ^ (l15 & 3)) << 3)];
#pragma unroll
      for (int pc = 0; pc < 4; ++pc)
        acc[st][pc] = __builtin_amdgcn_mfma_f32_16x16x32_bf16(ae, bv[pc],
                                                              acc[st][pc], 0,
                                                              0, 0);
    }
    __syncthreads();  // stage(it+1) complete; k/v reads of buf (it&1) done
  }
#undef STAGE_KV

  // ---- Row-sums across the 16 col-lanes.
#pragma unroll
  for (int st = 0; st < 2; ++st)
#pragma unroll
    for (int r = 0; r < 4; ++r) {
      float v = lpart[st][r];
      v += __shfl_xor(v, 1, 64);
      v += __shfl_xor(v, 2, 64);
      v += __shfl_xor(v, 4, 64);
      v += __shfl_xor(v, 8, 64);
      if (l15 == 0) l_s[w][st * 16 + l4 * 4 + r] = v;
    }

  // ---- Combine th-partials (pacc aliases k/v/e LDS; all reads done).
  float* pacc = (float*)smem;  // [4 qg][3][32][64]
  if (th > 0) {
#pragma unroll
    for (int st = 0; st < 2; ++st)
#pragma unroll
      for (int pc = 0; pc < 4; ++pc)
#pragma unroll
        for (int r = 0; r < 4; ++r)
          pacc[((size_t)(qg * 3 + th - 1) * 32 + st * 16 + l4 * 4 + r) * 64 +
               pc * 16 + l15] = acc[st][pc][r];
  }
  __syncthreads();

  unsigned short* wnorm = (unsigned short*)(smem + 98304);  // [128][72]
  if (th == 0) {
#pragma unroll
    for (int st = 0; st < 2; ++st) {
      float rl[4];
#pragma unroll
      for (int r = 0; r < 4; ++r) {
        const int row32 = st * 16 + l4 * 4 + r;
        rl[r] = 1.f / (l_s[qg][row32] + l_s[4 + qg][row32] +
                       l_s[8 + qg][row32] + l_s[12 + qg][row32]);
      }
#pragma unroll
      for (int pc = 0; pc < 4; ++pc)
#pragma unroll
        for (int r = 0; r < 4; ++r) {
          const int row32 = st * 16 + l4 * 4 + r;
          float s = acc[st][pc][r];
#pragma unroll
          for (int j = 0; j < 3; ++j)
            s += pacc[((size_t)(qg * 3 + j) * 32 + row32) * 64 + pc * 16 +
                      l15];
          wnorm[(qg * 32 + row32) * 72 + pc * 16 + l15] = f2bf(s * rl[r]);
        }
    }
  }
  __syncthreads();

  // ---- Fused output projection: wave = (rs=w&7: 16-row subtile) x
  // (chh=w>>3: 256-col half); Wo frags from global (1 KB coalesced).
  const int rs = w & 7;
  const int chh = w >> 3;
  const bf16x8 a0 = *(const bf16x8*)&wnorm[(rs * 16 + l15) * 72 + l4 * 8];
  const bf16x8 a1 = *(const bf16x8*)&wnorm[(rs * 16 + l15) * 72 + 32 + l4 * 8];
  const size_t orow0 = (size_t)b * S + s0 + rs * 16;
#pragma unroll
  for (int ct = 0; ct < 16; ++ct) {
    const int ctg = chh * 16 + ((ct + (blk & 15)) & 15);  // staggered
    const bf16x8 b0 =
        *(const bf16x8*)(Wofrag + ((size_t)(ctg * 2 + 0) * 64 + lane) * 8);
    const bf16x8 b1 =
        *(const bf16x8*)(Wofrag + ((size_t)(ctg * 2 + 1) * 64 + lane) * 8);
    f32x4 c = (f32x4){0.f, 0.f, 0.f, 0.f};
    c = __builtin_amdgcn_mfma_f32_16x16x32_bf16(a0, b0, c, 0, 0, 0);
    c = __builtin_amdgcn_mfma_f32_16x16x32_bf16(a1, b1, c, 0, 0, 0);
    const int col = ctg * 16 + l15;
    const float bb = bo[col];
#pragma unroll
    for (int r = 0; r < 4; ++r)
      out[(orow0 + l4 * 4 + r) * D + col] = c[r] + bb;
  }
}

// ---------------------------------------------------------------------------
extern "C" void kernel_launch(void* const* d_in, const int* in_sizes, int n_in,
                              void* d_out, int out_size, void* d_ws,
                              size_t ws_size, hipStream_t stream) {
  const float* query = (const float*)d_in[0];
  // d_in[1] = attention_mask: unused (per-row additive constant -> softmax no-op)
  const float* Wq = (const float*)d_in[2];
  const float* bq = (const float*)d_in[3];
  const float* Wk = (const float*)d_in[4];
  const float* bk = (const float*)d_in[5];
  const float* Wv = (const float*)d_in[6];
  const float* bv = (const float*)d_in[7];
  const float* Wo = (const float*)d_in[8];
  const float* bo = (const float*)d_in[9];
  float* out = (float*)d_out;

  // Workspace (bf16): qfrag 2MB | kfrag 2MB | vfrag 2MB | Bfrag 192KB | Wofrag 64KB
  const size_t proj = (size_t)B * S * P;  // 1,048,576
  unsigned short* qfr = (unsigned short*)d_ws;
  unsigned short* kfr = qfr + proj;
  unsigned short* vfr = kfr + proj;
  unsigned short* Bfrag = vfr + proj;
  unsigned short* Wofrag = Bfrag + 192 * 512;

  prep_w<<<384, 256, 0, stream>>>(Wq, Wk, Wv, Wo, Bfrag, Wofrag);
  qkv_mfma<<<256, 512, 0, stream>>>(query, Bfrag, bq, bk, bv, qfr, kfr, vfr);
  attn_fused<<<128, 1024, 0, stream>>>(qfr, kfr, vfr, Wofrag, bo, out);
}